// Round 6
// baseline (3786.489 us; speedup 1.0000x reference)
//
#include <hip/hip_runtime.h>
#include <stdint.h>

typedef _Float16 half_t;
typedef _Float16 half2v __attribute__((ext_vector_type(2)));
typedef _Float16 half8v __attribute__((ext_vector_type(8)));
typedef float    f32x4  __attribute__((ext_vector_type(4)));

#define Hd 512
#define Td 400
#define Sd 400
#define Bd 32

// ws layout (bytes)
#define OFF_BAR   0ull          // 16 groups x 32 u32 slots (128B/group) = 2048
#define OFF_HBUF  2048ull       // f16 [32][512] = 32768
#define OFF_PH    34816ull      // f32 [16][2][512] = 65536
#define OFF_CTXP  100352ull     // f32 [16][2][8][512] = 524288
#define OFF_LB    624640ull     // f32 [16][32] = 2048
#define ZERO_WORDS 8704         // bytes [0,34816): slots + hbuf
#define OFF_ENC   1048576ull    // f16 [400][32][512]
#define OFF_PENC  14155776ull   // f16 [400][32][512]
#define OFF_XS    27262976ull   // f16 [400][32][512]
#define OFF_GIX   40370176ull   // f16 [400][32][1536]
#define OFF_H2A   79691776ull   // f16 [400][32][512]
#define OFF_W1    92798976ull   // f16 [2048][512]  (fc_W rows 0-511, Whh rows 512-2047)
#define OFF_W3    94896128ull   // f16 [1536][512]  (Wih_c)
#define OFF_WX    96468992ull   // f16 [1536][512]  (Wih_x)
#define OFF_SPEC  98041856ull   // f16 [512][512]

#if __has_builtin(__builtin_amdgcn_fdot2)
#define FDOT2(a,b,c) __builtin_amdgcn_fdot2((a),(b),(c),false)
#else
static __device__ __forceinline__ float FDOT2(half2v a, half2v b, float c){
  return fmaf((float)a.x,(float)b.x, fmaf((float)a.y,(float)b.y,c));
}
#endif

static __device__ __forceinline__ float dot8(half8v a, half8v b, float acc){
  acc = FDOT2(__builtin_shufflevector(a,a,0,1), __builtin_shufflevector(b,b,0,1), acc);
  acc = FDOT2(__builtin_shufflevector(a,a,2,3), __builtin_shufflevector(b,b,2,3), acc);
  acc = FDOT2(__builtin_shufflevector(a,a,4,5), __builtin_shufflevector(b,b,4,5), acc);
  acc = FDOT2(__builtin_shufflevector(a,a,6,7), __builtin_shufflevector(b,b,6,7), acc);
  return acc;
}

static __device__ __forceinline__ float fast_tanh(float x){
  float t = __builtin_amdgcn_exp2f(x * 2.8853900817779268f);
  return fmaf(-2.f, __builtin_amdgcn_rcpf(t + 1.f), 1.f);
}
static __device__ __forceinline__ float fast_sigmoid(float x){
  float t = __builtin_amdgcn_exp2f(x * -1.4426950408889634f);
  return __builtin_amdgcn_rcpf(1.f + t);
}
// Pade tanh: clamp(+-3) then x(27+x^2)/(27+9x^2); |err|<=5e-3, 1 trans op.
static __device__ __forceinline__ float pade_tanh(float x){
  x = fminf(3.f, fmaxf(-3.f, x));
  float t2 = x * x;
  return (x * (27.f + t2)) * __builtin_amdgcn_rcpf(fmaf(t2, 9.f, 27.f));
}

// L1-bypassing relaxed loads (no cache-maintenance codegen)
static __device__ __forceinline__ float ld_f32_l2(const float* p){
  return __hip_atomic_load(p, __ATOMIC_RELAXED, __HIP_MEMORY_SCOPE_AGENT);
}
static __device__ __forceinline__ unsigned long long ld_u64_l2(const void* p){
  return __hip_atomic_load((const unsigned long long*)p, __ATOMIC_RELAXED,
                           __HIP_MEMORY_SCOPE_AGENT);
}

// ---------------- init: zero barrier slots + hbuf ------------------------
__global__ void k_init(char* ws){
  unsigned* p = (unsigned*)ws;
  int i = blockIdx.x*blockDim.x + threadIdx.x;
  if (i < ZERO_WORDS) p[i] = 0u;
}

// ---------------- prep: f32 -> f16 staging -------------------------------
__global__ void k_prep_enc(const float* __restrict__ src, half_t* __restrict__ dst, int n){
  int st = gridDim.x*blockDim.x;
  for (int i = blockIdx.x*blockDim.x + threadIdx.x; i < n; i += st)
    dst[i] = (half_t)src[i];
}
__global__ void k_prep_xs(const float* __restrict__ dec, half_t* __restrict__ dst){
  const int n = Td*Bd*Hd; int st = gridDim.x*blockDim.x;
  for (int i = blockIdx.x*blockDim.x + threadIdx.x; i < n; i += st){
    float v = (i < Bd*Hd) ? 0.f : dec[i - Bd*Hd];   // teacher forcing shift
    dst[i] = (half_t)v;
  }
}
__global__ void k_prep_w(const float* __restrict__ fcW, const float* __restrict__ Wih,
                         const float* __restrict__ Whh, const float* __restrict__ specW,
                         char* __restrict__ ws){
  half_t* w1 = (half_t*)(ws + OFF_W1);
  half_t* w3 = (half_t*)(ws + OFF_W3);
  half_t* wx = (half_t*)(ws + OFF_WX);
  half_t* sp = (half_t*)(ws + OFF_SPEC);
  int st = gridDim.x*blockDim.x;
  int t0 = blockIdx.x*blockDim.x + threadIdx.x;
  for (int i = t0; i < 2048*512; i += st)
    w1[i] = (half_t)((i < 512*512) ? fcW[i] : Whh[i - 512*512]);
  for (int i = t0; i < 1536*512; i += st){
    int r = i >> 9, k = i & 511;
    wx[i] = (half_t)Wih[r*1024 + k];
    w3[i] = (half_t)Wih[r*1024 + 512 + k];
  }
  for (int i = t0; i < 512*512; i += st) sp[i] = (half_t)specW[i];
}

// ---------------- bulk MFMA GEMM: C[M,N] = A[M,512] @ W[N,512]^T ---------
template<int MODE>
__global__ __launch_bounds__(256) void k_gemm(const half_t* __restrict__ A,
                                              const half_t* __restrict__ W,
                                              void* __restrict__ out, int N,
                                              const float* __restrict__ bias)
{
  __shared__ __align__(16) half_t As[64*32];
  __shared__ __align__(16) half_t Ws[64*32];
  const int tid = threadIdx.x;
  const int m0 = blockIdx.y * 64, n0 = blockIdx.x * 64;
  const int trow = tid >> 2, tseg = tid & 3;
  const int wv = tid >> 6, ln = tid & 63;
  const int fr = ln & 15, ko = (ln >> 4) * 8;
  f32x4 acc[4];
  #pragma unroll
  for (int cb = 0; cb < 4; ++cb){ acc[cb][0]=0.f; acc[cb][1]=0.f; acc[cb][2]=0.f; acc[cb][3]=0.f; }
  for (int kk = 0; kk < 512; kk += 32){
    ((uint4*)As)[tid] = *(const uint4*)(A + (size_t)(m0 + trow)*512 + kk + tseg*8);
    ((uint4*)Ws)[tid] = *(const uint4*)(W + (size_t)(n0 + trow)*512 + kk + tseg*8);
    __syncthreads();
    half8v af = *(const half8v*)&As[(wv*16 + fr)*32 + ko];
    #pragma unroll
    for (int cb = 0; cb < 4; ++cb){
      half8v bf = *(const half8v*)&Ws[(cb*16 + fr)*32 + ko];
      acc[cb] = __builtin_amdgcn_mfma_f32_16x16x32_f16(af, bf, acc[cb], 0, 0, 0);
    }
    __syncthreads();
  }
  #pragma unroll
  for (int cb = 0; cb < 4; ++cb){
    #pragma unroll
    for (int i = 0; i < 4; ++i){
      int gr = m0 + wv*16 + (ln >> 4)*4 + i;
      int gc = n0 + cb*16 + (ln & 15);
      if (MODE == 0){
        ((half_t*)out)[(size_t)gr*N + gc] = (half_t)acc[cb][i];
      } else {
        int tt = gr >> 5, bb = gr & 31;
        ((float*)out)[(size_t)bb*(Td*Hd) + (size_t)tt*Hd + gc] = acc[cb][i] + bias[gc];
      }
    }
  }
}

// ---------------- gate projection ---------------------------------------
__global__ __launch_bounds__(256) void k_gate(const half_t* __restrict__ h2a,
    const float* __restrict__ gW, const float* __restrict__ gb, float* __restrict__ out)
{
  const int o = blockIdx.x * 4 + (threadIdx.x >> 6);
  const int lane = threadIdx.x & 63;
  const half8v hv = *(const half8v*)(h2a + (size_t)o*512 + lane*8);
  float a = 0.f;
  #pragma unroll
  for (int i = 0; i < 8; ++i) a = fmaf((float)hv[i], gW[lane*8 + i], a);
  #pragma unroll
  for (int o2 = 1; o2 < 64; o2 <<= 1) a += __shfl_xor(a, o2);
  if (lane == 0){
    const int tt = o >> 5, bb = o & 31;
    out[Bd*Td*Hd + bb*Td + tt] = a + gb[0];
  }
}

// ---------------- barrier primitives (distributed slots, no RMW) ---------
static __device__ __forceinline__ void slot_store(unsigned* slots, int r, unsigned v){
  __hip_atomic_store(&slots[r], v, __ATOMIC_RELAXED, __HIP_MEMORY_SCOPE_AGENT);
}
static __device__ __forceinline__ void wait_slots(unsigned* slots, unsigned v){
  if (threadIdx.x < 64){
    const unsigned* sp = &slots[threadIdx.x & 15];
    for (;;){
      unsigned x = __hip_atomic_load(sp, __ATOMIC_RELAXED, __HIP_MEMORY_SCOPE_AGENT);
      if (__all((int)(x >= v))) break;
      __builtin_amdgcn_s_sleep(1);
    }
  }
  __syncthreads();
}

// ---------------- persistent recurrent kernel ----------------------------
// 256 blocks x 512 thr, 1 block/CU. 16 groups x 16 members; group g handles
// batches {2g, 2g+1}. Members share one XCD (blockIdx&7 under round-robin).
// Member r: ph rows [32r,32r+32), GRU j-slice [32r,32r+32), score chunk
// (b_l=r&1, ch=r>>1) of 50 s. All matvecs = v_dot2 with register-resident
// weight K-slices; Penc/enc tiles LDS-resident; gix prefetched 1 step ahead.
__global__ __launch_bounds__(512, 2) void k_main(char* __restrict__ ws,
                                                 const float* __restrict__ attw)
{
  const int bid = blockIdx.x;
  const int ixd = bid >> 3;
  const int r   = ixd & 15;
  const int g   = (bid & 7)*2 + (ixd >> 4);
  const int b0g = g*2;
  const int tid = threadIdx.x;
  const int lane = tid & 63;
  const int w  = tid >> 6;
  const int rw = tid >> 4;        // 0..31 row-in-slice
  const int p  = tid & 15;        // K partition (32 halfs each)
  const int b_l = r & 1, ch = r >> 1;
  const int bglob = b0g + b_l;

  half_t* hbuf = (half_t*)(ws + OFF_HBUF);
  float*  ph_g = (float*)(ws + OFF_PH)   + g*1024;     // [2][512]
  float*  ctxp = (float*)(ws + OFF_CTXP) + g*8192;     // [2][8][512]
  float*  lbp  = (float*)(ws + OFF_LB)   + g*32;       // [b*8+ch]
  unsigned* slots = (unsigned*)(ws + OFF_BAR) + g*32;
  const half_t* Penc = (const half_t*)(ws + OFF_PENC);
  const half_t* ench = (const half_t*)(ws + OFF_ENC);
  const half_t* gix  = (const half_t*)(ws + OFF_GIX);
  half_t* h2a = (half_t*)(ws + OFF_H2A);
  const half_t* w1 = (const half_t*)(ws + OFF_W1);
  const half_t* w3 = (const half_t*)(ws + OFF_W3);

  // ---- LDS (~115 KB) ----------------------------------------------------
  __shared__ __align__(16) half_t PT[50*512];      // Penc tile [s][512]
  __shared__ __align__(16) half_t ETT[512*56];     // enc tile  [h][s]
  __shared__ __align__(16) half_t hs[2*512];       // h staging
  __shared__ __align__(16) half_t ctxs[2*512];     // normalized ctx
  __shared__ __align__(16) float ghb[3][2][32];
  __shared__ __align__(16) float gib[3][2][32];
  __shared__ __align__(16) float es[64];
  __shared__ float Ls[2];

  // ---- pre-loop: stage Penc / enc tiles ---------------------------------
  for (int i = tid; i < 50*64; i += 512){
    int s = i >> 6, c = i & 63;
    ((uint4*)PT)[s*64 + c] =
      *(const uint4*)(Penc + ((size_t)((ch*50 + s)*32 + bglob))*512 + c*8);
  }
  {
    const half_t* eb = ench + ((size_t)(ch*50)*32 + bglob)*512;
    for (int s = 0; s < 50; ++s)
      ETT[tid*56 + s] = eb[(size_t)s*16384 + tid];
  }

  // ---- register-resident weight K-slices --------------------------------
  half8v w1r[4], whr[3][4], w3r[3][4];
  {
    const half_t* wp = w1 + (size_t)(32*r + rw)*512 + p*32;
    #pragma unroll
    for (int q = 0; q < 4; ++q) w1r[q] = *(const half8v*)(wp + q*8);
    #pragma unroll
    for (int gate = 0; gate < 3; ++gate){
      const half_t* wh = w1 + (size_t)(512 + gate*512 + 32*r + rw)*512 + p*32;
      const half_t* wc = w3 + (size_t)(gate*512 + 32*r + rw)*512 + p*32;
      #pragma unroll
      for (int q = 0; q < 4; ++q){
        whr[gate][q] = *(const half8v*)(wh + q*8);
        w3r[gate][q] = *(const half8v*)(wc + q*8);
      }
    }
  }
  float awr[8];
  #pragma unroll
  for (int i = 0; i < 8; ++i) awr[i] = attw[lane*8 + i];

  const int s0 = (w < 2) ? 7*w : 14 + 6*(w-2);   // 50 = 2*7 + 6*6
  const int ns = (w < 2) ? 7 : 6;
  float h2keep = 0.f;
  // gix prefetch for t=0 (zeros row of xs contributes via GI_x; still load)
  float gxr = 0.f, gxz = 0.f, gxn = 0.f;
  if (tid < 64){
    const int bl = tid >> 5, jj = tid & 31, j = 32*r + jj;
    const half_t* gp = gix + ((size_t)(b0g + bl))*1536;
    gxr = (float)gp[j]; gxz = (float)gp[512 + j]; gxn = (float)gp[1024 + j];
  }
  __syncthreads();   // LDS tiles ready

  for (int t = 0; t < Td; ++t){
    // ===== wait barrier C of previous step ==============================
    wait_slots(slots, 3u*(unsigned)t);
    // ===== phase 1: ph rows [32r,32r+32) via dot2, split-K over 16 p ====
    if (tid < 256)
      ((unsigned long long*)hs)[tid] =
        ld_u64_l2(((const unsigned long long*)(hbuf + b0g*512)) + tid);
    __syncthreads();
    half8v h8[2][4];
    #pragma unroll
    for (int bb = 0; bb < 2; ++bb)
      #pragma unroll
      for (int q = 0; q < 4; ++q)
        h8[bb][q] = *(const half8v*)(hs + bb*512 + p*32 + q*8);
    {
      float a0 = 0.f, a1 = 0.f;
      #pragma unroll
      for (int q = 0; q < 4; ++q){
        a0 = dot8(w1r[q], h8[0][q], a0);
        a1 = dot8(w1r[q], h8[1][q], a1);
      }
      #pragma unroll
      for (int o = 1; o < 16; o <<= 1){ a0 += __shfl_xor(a0, o); a1 += __shfl_xor(a1, o); }
      if (p == 0){ ph_g[32*r + rw] = a0; ph_g[512 + 32*r + rw] = a1; }
    }
    __syncthreads();                      // drains vmcnt: ph L2-visible
    if (tid == 0) slot_store(slots, r, 3u*t + 1u);
    // gh in barrier shadow (registers + LDS only)
    #pragma unroll
    for (int gate = 0; gate < 3; ++gate){
      float a0 = 0.f, a1 = 0.f;
      #pragma unroll
      for (int q = 0; q < 4; ++q){
        a0 = dot8(whr[gate][q], h8[0][q], a0);
        a1 = dot8(whr[gate][q], h8[1][q], a1);
      }
      #pragma unroll
      for (int o = 1; o < 16; o <<= 1){ a0 += __shfl_xor(a0, o); a1 += __shfl_xor(a1, o); }
      if (p == 0){ ghb[gate][0][rw] = a0; ghb[gate][1][rw] = a1; }
    }
    wait_slots(slots, 3u*t + 1u);
    // ===== phase 2: scores + fixed-offset softmax + ctx partial =========
    {
      union { unsigned long long u[4]; float f[8]; } phu;
      const float* php = ph_g + b_l*512 + lane*8;
      #pragma unroll
      for (int q2 = 0; q2 < 4; ++q2)
        phu.u[q2] = ld_u64_l2(((const unsigned long long*)php) + q2);
      #pragma unroll
      for (int k = 0; k < 7; ++k){
        if (k >= ns) break;
        const int s_l = s0 + k;
        half8v pvv = *(const half8v*)(PT + s_l*512 + lane*8);
        float a = 0.f;
        #pragma unroll
        for (int i = 0; i < 8; ++i)
          a = fmaf(pade_tanh((float)pvv[i] + phu.f[i]), awr[i], a);
        #pragma unroll
        for (int o = 1; o < 64; o <<= 1) a += __shfl_xor(a, o);
        if (lane == 0) es[s_l] = a;
      }
      __syncthreads();
      if (tid < 64){
        float ev = 0.f;
        if (tid < 50){
          ev = __builtin_amdgcn_exp2f((es[tid] - 20.f) * 1.4426950408889634f);
          es[tid] = ev;    // fixed-offset softmax (|e| <= ||att_w||_1 ~ 18)
        }
        #pragma unroll
        for (int o = 1; o < 64; o <<= 1) ev += __shfl_xor(ev, o);
        if (tid == 0) lbp[b_l*8 + ch] = ev;
      }
      __syncthreads();
      const half_t* rowp = ETT + tid*56;
      float acc2 = 0.f;
      #pragma unroll
      for (int q = 0; q < 6; ++q){
        half8v r8 = *(const half8v*)(rowp + q*8);
        #pragma unroll
        for (int e = 0; e < 8; ++e) acc2 = fmaf((float)r8[e], es[q*8 + e], acc2);
      }
      acc2 = fmaf((float)rowp[48], es[48], acc2);
      acc2 = fmaf((float)rowp[49], es[49], acc2);
      ctxp[(b_l*8 + ch)*512 + tid] = acc2;
    }
    __syncthreads();                      // drains ctxp/lbp stores
    if (tid == 0) slot_store(slots, r, 3u*t + 2u);
    wait_slots(slots, 3u*t + 2u);
    // ===== phase 3: gather ctx, normalize, gi_c dot2, GRU update ========
    if (tid < 16){
      float v = ld_f32_l2(&lbp[tid]);
      v += __shfl_xor(v, 1); v += __shfl_xor(v, 2); v += __shfl_xor(v, 4);
      if ((tid & 7) == 0) Ls[tid >> 3] = __builtin_amdgcn_rcpf(v);
    }
    float sum0 = 0.f, sum1 = 0.f;
    #pragma unroll
    for (int c2 = 0; c2 < 8; ++c2){
      sum0 += ld_f32_l2(&ctxp[c2*512 + tid]);
      sum1 += ld_f32_l2(&ctxp[4096 + c2*512 + tid]);
    }
    __syncthreads();                      // Ls ready
    ctxs[tid]       = (half_t)(sum0 * Ls[0]);
    ctxs[512 + tid] = (half_t)(sum1 * Ls[1]);
    __syncthreads();
    {
      half8v c8[2][4];
      #pragma unroll
      for (int bb = 0; bb < 2; ++bb)
        #pragma unroll
        for (int q = 0; q < 4; ++q)
          c8[bb][q] = *(const half8v*)(ctxs + bb*512 + p*32 + q*8);
      #pragma unroll
      for (int gate = 0; gate < 3; ++gate){
        float a0 = 0.f, a1 = 0.f;
        #pragma unroll
        for (int q = 0; q < 4; ++q){
          a0 = dot8(w3r[gate][q], c8[0][q], a0);
          a1 = dot8(w3r[gate][q], c8[1][q], a1);
        }
        #pragma unroll
        for (int o = 1; o < 16; o <<= 1){ a0 += __shfl_xor(a0, o); a1 += __shfl_xor(a1, o); }
        if (p == 0){ gib[gate][0][rw] = a0; gib[gate][1][rw] = a1; }
      }
    }
    __syncthreads();
    if (tid < 64){
      const int bl = tid >> 5, jj = tid & 31;
      const int j = 32*r + jj, bg = b0g + bl;
      float xr = gxr + gib[0][bl][jj] + ghb[0][bl][jj];
      float xz = gxz + gib[1][bl][jj] + ghb[1][bl][jj];
      float xn = gxn + gib[2][bl][jj];
      float gnh = ghb[2][bl][jj];
      float rr = fast_sigmoid(xr);
      float z  = fast_sigmoid(xz);
      float n  = fast_tanh(xn + rr * gnh);
      float h2v = (1.f - z) * n + z * h2keep;
      h2keep = h2v;
      hbuf[bg*512 + j] = (half_t)h2v;
      h2a[((size_t)t*32 + bg)*512 + j] = (half_t)h2v;
      // prefetch gix for t+1 (held in regs across barrier C)
      const int tn = (t + 1 < Td) ? t + 1 : t;
      const half_t* gp = gix + ((size_t)tn*32 + bg)*1536;
      gxr = (float)gp[j]; gxz = (float)gp[512 + j]; gxn = (float)gp[1024 + j];
    }
    __syncthreads();                      // drains h2/h2a stores
    if (tid == 0) slot_store(slots, r, 3u*t + 3u);
  }
}

// ---------------- launch --------------------------------------------------
extern "C" void kernel_launch(void* const* d_in, const int* in_sizes, int n_in,
                              void* d_out, int out_size, void* d_ws, size_t ws_size,
                              hipStream_t stream)
{
  const float* dec   = (const float*)d_in[0];
  const float* enc   = (const float*)d_in[1];
  const float* fcW   = (const float*)d_in[2];
  const float* attw  = (const float*)d_in[3];
  const float* Wih   = (const float*)d_in[4];
  const float* Whh   = (const float*)d_in[5];
  const float* specW = (const float*)d_in[6];
  const float* specb = (const float*)d_in[7];
  const float* gateW = (const float*)d_in[8];
  const float* gateb = (const float*)d_in[9];
  char* ws = (char*)d_ws;
  float* out = (float*)d_out;

  hipLaunchKernelGGL(k_init, dim3(34), dim3(256), 0, stream, ws);
  hipLaunchKernelGGL(k_prep_enc, dim3(2048), dim3(256), 0, stream,
                     enc, (half_t*)(ws + OFF_ENC), Sd*Bd*Hd);
  hipLaunchKernelGGL(k_prep_xs, dim3(2048), dim3(256), 0, stream,
                     dec, (half_t*)(ws + OFF_XS));
  hipLaunchKernelGGL(k_prep_w, dim3(1024), dim3(256), 0, stream,
                     fcW, Wih, Whh, specW, ws);
  // Penc = enc @ fc_W^T   (M=12800, N=512)
  hipLaunchKernelGGL((k_gemm<0>), dim3(8, 200), dim3(256), 0, stream,
                     (const half_t*)(ws + OFF_ENC), (const half_t*)(ws + OFF_W1),
                     (void*)(ws + OFF_PENC), 512, (const float*)nullptr);
  // GI_x = xs @ Wih_x^T   (M=12800, N=1536)
  hipLaunchKernelGGL((k_gemm<0>), dim3(24, 200), dim3(256), 0, stream,
                     (const half_t*)(ws + OFF_XS), (const half_t*)(ws + OFF_WX),
                     (void*)(ws + OFF_GIX), 1536, (const float*)nullptr);
  // recurrent loop
  hipLaunchKernelGGL(k_main, dim3(256), dim3(512), 0, stream, ws, attw);
  // mels = h2 @ spec_W^T + b, written (B,T,H)
  hipLaunchKernelGGL((k_gemm<1>), dim3(8, 200), dim3(256), 0, stream,
                     (const half_t*)(ws + OFF_H2A), (const half_t*)(ws + OFF_SPEC),
                     (void*)out, 512, specb);
  // gates = h2 @ gate_W + b, written (B,T)
  hipLaunchKernelGGL(k_gate, dim3(3200), dim3(256), 0, stream,
                     (const half_t*)(ws + OFF_H2A), gateW, gateb, out);
}